// Round 9
// baseline (84.409 us; speedup 1.0000x reference)
//
#include <hip/hip_runtime.h>

// x[B=32, C=512, H=256, W=14] f32. Per-(b,h) shuffle of the 7 same-parity
// columns (p = h%2): out[b,c,h,2j+p] = x[b,c,h,2*perm[b,h,j]+p]; other
// columns identity. Pure within-row (56 B) gather, broadcast over C.
//
// Round 9 = round 8 with ONE change: plain (L2-allocating) stores instead of
// __builtin_nontemporal_store, to isolate the nt flag's effect on the write
// stream (L2 write-combining hypothesis).
//
// Structure (unchanged from round 8):
//  - TILE = 256 rows; LDS = 14336 B tile + 4096 B cmap = 18432 B ->
//    8 blocks/CU, 32 waves/CU; grid 16384 = exactly 8 rounds.
//  - Wave-private, no barriers; wave owns 64 rows = 896 floats.
//  - Bijective 64-float gather windows: lane l produces slice float 64j+l;
//    per-row permutation => each window's 64 LDS reads hit 64 distinct
//    words (~2 lanes/bank, conflict-free).
//  - perm loads issued BEFORE the 4 DMA chunks (vmcnt FIFO ordering).
//  - counted waits: vmcnt(3)@j0, (2)@j3, (1)@j7, (0)@j10.

#define TILE_ROWS   256
#define TILE_FLOATS (TILE_ROWS * 14)   // 3584 floats = 14336 B
#define WAVE_F      896                // floats per wave (64 rows)
#define WAVE_V4     224                // float4 per wave

typedef float v4f __attribute__((ext_vector_type(4)));

#define GLOAD_LDS16(gp, lp)                                                   \
    __builtin_amdgcn_global_load_lds(                                         \
        (const __attribute__((address_space(1))) void*)(gp),                  \
        (__attribute__((address_space(3))) void*)(lp), 16, 0, 0)

__global__ __launch_bounds__(256, 8) void GSRS_shuffle_win9_kernel(
    const float* __restrict__ x,
    const int* __restrict__ perms,
    float* __restrict__ out)
{
    __shared__ float tile[TILE_FLOATS];        // 14336 B
    __shared__ unsigned char cmap[256][16];    // 4096 B  (total 18432 B)

    const unsigned tid  = threadIdx.x;
    const unsigned lane = tid & 63u;
    const unsigned wv   = tid >> 6;            // wave id 0..3
    const unsigned tb   = blockIdx.x;          // tile index, 0..16383
    const unsigned base = tb * TILE_FLOATS;    // float offset of tile
    const unsigned b    = tb >> 9;             // batch (512 tiles/batch)

    // ---- perm loads FIRST (older than DMAs in the vmcnt FIFO).
    // Thread tid owns cmap row h = tid: 7 consecutive ints.
    const int* pr = perms + b * 1792u + tid * 7u;
    int pm[7];
#pragma unroll
    for (int j = 0; j < 7; ++j) pm[j] = pr[j];
    __builtin_amdgcn_sched_barrier(0);         // pin: perms older than DMAs

    // ---- issue 4 DMA chunks (56 active lanes each: 224 float4 per wave,
    // LDS dest linear = wave-uniform base + lane*16).
    const v4f* xv = reinterpret_cast<const v4f*>(x + base);
    v4f*       tv = reinterpret_cast<v4f*>(tile);
    if (lane < 56u) {
#pragma unroll
        for (int c = 0; c < 4; ++c)
            GLOAD_LDS16(xv + wv * WAVE_V4 + c * 56 + lane,
                        tv + wv * WAVE_V4 + c * 56 + lane);
    }
    __builtin_amdgcn_sched_barrier(0);         // pin: DMAs issued before cmap

    // ---- cmap build overlaps DMA flight (compiler waits vmcnt(4) for pm
    // only). Row h = tid; p = h&1; src column byte per output column.
    {
        const unsigned p = tid & 1u;
        union { unsigned char c[16]; uint4 v; } u;
#pragma unroll
        for (int w14 = 0; w14 < 14; ++w14) {
            unsigned src = (((unsigned)w14 & 1u) == p)
                ? 2u * (unsigned)pm[w14 >> 1] + p
                : (unsigned)w14;
            u.c[w14] = (unsigned char)src;
        }
        u.c[14] = 0; u.c[15] = 0;
        *reinterpret_cast<uint4*>(&cmap[tid][0]) = u.v;  // ds_write_b128
    }

    // ---- windowed gather: lane l produces slice float 64j + l.
    float vbuf[14];
#pragma unroll
    for (int j = 0; j < 14; ++j) {
        if (j == 0)  { asm volatile("s_waitcnt vmcnt(3)" ::: "memory");
                       __builtin_amdgcn_sched_barrier(0); }
        if (j == 3)  { asm volatile("s_waitcnt vmcnt(2)" ::: "memory");
                       __builtin_amdgcn_sched_barrier(0); }
        if (j == 7)  { asm volatile("s_waitcnt vmcnt(1)" ::: "memory");
                       __builtin_amdgcn_sched_barrier(0); }
        if (j == 10) { asm volatile("s_waitcnt vmcnt(0)" ::: "memory");
                       __builtin_amdgcn_sched_barrier(0); }
        const unsigned o    = (unsigned)j * 64u + lane;  // slice float index
        const unsigned lrow = o / 14u;                   // row within wave slice
        const unsigned w14  = o - lrow * 14u;
        const unsigned h    = wv * 64u + lrow;           // == local tile row
        const unsigned src  = cmap[h][w14];              // ds_read_u8
        vbuf[j] = tile[h * 14u + src];                   // bijective 64-word window
    }

    // ---- plain coalesced dword stores (L2-allocating; write combining on).
    float* op = out + base + wv * WAVE_F + lane;
#pragma unroll
    for (int j = 0; j < 14; ++j)
        op[j * 64] = vbuf[j];
}

extern "C" void kernel_launch(void* const* d_in, const int* in_sizes, int n_in,
                              void* d_out, int out_size, void* d_ws, size_t ws_size,
                              hipStream_t stream) {
    const float* x     = (const float*)d_in[0];
    const int*   perms = (const int*)d_in[1];
    float*       out   = (float*)d_out;

    // 4,194,304 rows / 256 rows per tile = 16384 tiles, one block each.
    hipLaunchKernelGGL(GSRS_shuffle_win9_kernel, dim3(16384), dim3(256), 0, stream,
                       x, perms, out);
}

// Round 10
// 71.903 us; speedup vs baseline: 1.1739x; 1.1739x over previous
//
#include <hip/hip_runtime.h>

// x[B=32, C=512, H=256, W=14] f32. Per-(b,h) shuffle of the 7 same-parity
// columns (p = h%2): out[b,c,h,2j+p] = x[b,c,h,2*perm[b,h,j]+p]; other
// columns identity. Pure within-row (56 B) gather, broadcast over C.
//
// Round 10: DIRECT global gather (no x tile in LDS) + nt stores.
// Tests whether the ~72 us plateau is an external memory bound or an
// artifact of the global_load_lds staging path.
//  - Per-row permutation => a wave's 64 gather addresses in window j are a
//    bijection onto a contiguous ~64-90-word span: near-coalesced; extra
//    touched lines are used by adjacent windows (L1/L2 absorb).
//  - cmap[h][w] (4 KB LDS) built wave-private (thread tid owns row tid; wave
//    reads only its own 64 rows) -> one wave-local lgkmcnt(0), no barriers.
//  - 14 ds_read_u8 -> 14 independent global_load_dword -> 14 nt stores per
//    lane; at 32 waves/CU all latency is overlapped.
//  - LDS = 4 KB; grid 16384 x 256 = 8 full scheduling rounds.

#define TILE_ROWS   256
#define TILE_FLOATS (TILE_ROWS * 14)   // 3584 floats
#define WAVE_F      896                // floats per wave (64 rows)

__global__ __launch_bounds__(256, 8) void GSRS_shuffle_dg10_kernel(
    const float* __restrict__ x,
    const int* __restrict__ perms,
    float* __restrict__ out)
{
    __shared__ unsigned char cmap[256][16];    // 4096 B total LDS

    const unsigned tid  = threadIdx.x;
    const unsigned lane = tid & 63u;
    const unsigned wv   = tid >> 6;            // wave id 0..3
    const unsigned tb   = blockIdx.x;          // tile index, 0..16383
    const unsigned base = tb * TILE_FLOATS;    // float offset of tile
    const unsigned b    = tb >> 9;             // batch (512 tiles/batch)

    // ---- cmap build: thread tid owns row h = tid (7 consecutive ints).
    {
        const int* pr = perms + b * 1792u + tid * 7u;
        int pm[7];
#pragma unroll
        for (int j = 0; j < 7; ++j) pm[j] = pr[j];
        const unsigned p = tid & 1u;
        union { unsigned char c[16]; uint4 v; } u;
#pragma unroll
        for (int w14 = 0; w14 < 14; ++w14) {
            unsigned src = (((unsigned)w14 & 1u) == p)
                ? 2u * (unsigned)pm[w14 >> 1] + p
                : (unsigned)w14;
            u.c[w14] = (unsigned char)src;
        }
        u.c[14] = 0; u.c[15] = 0;
        *reinterpret_cast<uint4*>(&cmap[tid][0]) = u.v;  // ds_write_b128
    }
    // Wave-private visibility: wave wv reads only cmap rows [wv*64, wv*64+64),
    // all written by this wave's own threads. Wave-local drain suffices.
    asm volatile("s_waitcnt lgkmcnt(0)" ::: "memory");
    __builtin_amdgcn_sched_barrier(0);

    // ---- source columns for this lane's 14 output elements (ds_read_u8).
    unsigned srcf[14];
#pragma unroll
    for (int j = 0; j < 14; ++j) {
        const unsigned o    = (unsigned)j * 64u + lane;  // slice float index
        const unsigned lrow = o / 14u;
        const unsigned w14  = o - lrow * 14u;
        const unsigned h    = wv * 64u + lrow;
        srcf[j] = (unsigned)cmap[h][w14] + h * 14u;      // float idx in tile
    }

    // ---- 14 independent near-coalesced gather loads from global.
    const float* xt = x + base;
    float vbuf[14];
#pragma unroll
    for (int j = 0; j < 14; ++j)
        vbuf[j] = xt[srcf[j]];

    // ---- nontemporal coalesced dword stores (256 B per wave-inst).
    float* op = out + base + wv * WAVE_F + lane;
#pragma unroll
    for (int j = 0; j < 14; ++j)
        __builtin_nontemporal_store(vbuf[j], op + j * 64);
}

extern "C" void kernel_launch(void* const* d_in, const int* in_sizes, int n_in,
                              void* d_out, int out_size, void* d_ws, size_t ws_size,
                              hipStream_t stream) {
    const float* x     = (const float*)d_in[0];
    const int*   perms = (const int*)d_in[1];
    float*       out   = (float*)d_out;

    // 4,194,304 rows / 256 rows per tile = 16384 tiles, one block each.
    hipLaunchKernelGGL(GSRS_shuffle_dg10_kernel, dim3(16384), dim3(256), 0, stream,
                       x, perms, out);
}